// Round 2
// baseline (84996.216 us; speedup 1.0000x reference)
//
#include <hip/hip_runtime.h>
#include <cstdint>
#include <cstddef>

// GRU decoder w/ Bahdanau attention, B=64 L=512 E=128 H=512 ENC=256 V=4 NL=2.
// R2: persistent cooperative kernel; keys pinned in LDS (swizzled), all weight
// slices + enc slice pinned in registers (weights-stationary matvecs),
// q_part exchange in bf16. 3 grid barriers/step.

#define BB   64
#define LL   512
#define EE   128
#define HH   512
#define ED   256
#define VV   4
#define SOS  4

#define NBLK 256
#define NTHR 512

typedef unsigned short ushort8 __attribute__((ext_vector_type(8)));
typedef unsigned int uint;

// ---------------- ws layout (bytes) ----------------
static const size_t OFF_KEYS = 0;          // ushort [B][L][H]    33,554,432
static const size_t OFF_WH   = 50331648;   // ushort [H][H]          524,288
static const size_t OFF_WHH0 = 50855936;   // ushort [3H][H]       1,572,864
static const size_t OFF_WIH1 = 52428800;   // ushort [3H][H]       1,572,864
static const size_t OFF_WHH1 = 54001664;   // ushort [3H][H]       1,572,864
static const size_t OFF_WIHC = 55574528;   // ushort [3H][ED]        786,432
static const size_t OFF_GTOK = 56360960;   // float  [6][3H]          36,864
static const size_t OFF_H0   = 56397824;   // float  [B][H]
static const size_t OFF_H1   = 56528896;   // float  [B][H]
static const size_t OFF_GH0  = 56659968;   // float  [B][3H]
static const size_t OFF_GH1  = 57053184;   // float  [B][3H]
static const size_t OFF_CTXP = 57446400;   // float  [4][B][ED]
static const size_t OFF_SMMS = 57708544;   // float  [4][B][2]
static const size_t OFF_QP   = 57710592;   // ushort [32][B][H]    2,097,152
static const size_t OFF_LP   = 61904896;   // float  [L][32][B*V] 16,777,216
static const size_t OFF_BAR  = 78682112;   // 18 x 64B barrier lines

// ---------------- dynamic LDS layout (bytes) ----------------
#define L_KEYS 0          // 131072 : swizzled keys [128][512] bf16
#define L_Q    131072     // 2048   : q[512] f32
#define L_VV   133120     // 2048   : v[512] f32
#define L_SC   135168     // 512    : scores[128]
#define L_AT   135680     // 512    : attn[128]
#define L_SCR  136192     // 16384  : phase scratch
#define L_TOT  152576

// ---------------- helpers ----------------
__device__ __forceinline__ float bfu(unsigned short u) {
  return __uint_as_float(((unsigned)u) << 16);
}
__device__ __forceinline__ float bflo(uint u) { return __uint_as_float(u << 16); }
__device__ __forceinline__ float bfhi(uint u) { return __uint_as_float(u & 0xffff0000u); }
__device__ __forceinline__ unsigned short f2bf(float f) {
  unsigned u = __float_as_uint(f);
  unsigned r = 0x7FFFu + ((u >> 16) & 1u);
  return (unsigned short)((u + r) >> 16);
}
__device__ __forceinline__ float tanh_fast(float x) {
  x = __builtin_amdgcn_fmed3f(x, -10.f, 10.f);
  float t = __builtin_amdgcn_exp2f(x * 2.8853900817779268f); // e^{2x}
  return (t - 1.f) * __builtin_amdgcn_rcpf(t + 1.f);
}
__device__ __forceinline__ float sigmoid_fast(float x) {
  x = __builtin_amdgcn_fmed3f(x, -30.f, 30.f);
  float t = __builtin_amdgcn_exp2f(x * -1.4426950408889634f);
  return __builtin_amdgcn_rcpf(1.f + t);
}
__device__ __forceinline__ float exp_fast(float x) {
  return __builtin_amdgcn_exp2f(x * 1.4426950408889634f);
}

// two-level grid barrier: 16 groups of 16 blocks, then master, then release.
__device__ __forceinline__ void grid_barrier(char* barbase, unsigned gen) {
  __syncthreads();
  if (threadIdx.x == 0) {
    unsigned* grpc = (unsigned*)(barbase + (size_t)(blockIdx.x >> 4) * 64);
    unsigned* mstc = (unsigned*)(barbase + 16 * 64);
    unsigned* rel  = (unsigned*)(barbase + 17 * 64);
    __threadfence();
    bool last = false;
    unsigned p = __hip_atomic_fetch_add(grpc, 1u, __ATOMIC_ACQ_REL, __HIP_MEMORY_SCOPE_AGENT);
    if (p == 15u) {
      unsigned q = __hip_atomic_fetch_add(mstc, 1u, __ATOMIC_ACQ_REL, __HIP_MEMORY_SCOPE_AGENT);
      if (q == 15u) {
        #pragma unroll
        for (int g = 0; g < 16; ++g)
          __hip_atomic_store((unsigned*)(barbase + (size_t)g * 64), 0u, __ATOMIC_RELAXED, __HIP_MEMORY_SCOPE_AGENT);
        __hip_atomic_store(mstc, 0u, __ATOMIC_RELAXED, __HIP_MEMORY_SCOPE_AGENT);
        __hip_atomic_store(rel, gen, __ATOMIC_RELEASE, __HIP_MEMORY_SCOPE_AGENT);
        last = true;
      }
    }
    if (!last) {
      while (__hip_atomic_load(rel, __ATOMIC_ACQUIRE, __HIP_MEMORY_SCOPE_AGENT) < gen)
        __builtin_amdgcn_s_sleep(1);
    }
    __threadfence();
  }
  __syncthreads();
}

// ---------------- precompute kernels ----------------

__global__ void k_prep(const float* Wh, const float* Whh0, const float* Wih0,
                       const float* Wih1, const float* Whh1, char* ws) {
  unsigned short* Whbf   = (unsigned short*)(ws + OFF_WH);
  unsigned short* Whh0bf = (unsigned short*)(ws + OFF_WHH0);
  unsigned short* Wih1bf = (unsigned short*)(ws + OFF_WIH1);
  unsigned short* Whh1bf = (unsigned short*)(ws + OFF_WHH1);
  unsigned short* WihCbf = (unsigned short*)(ws + OFF_WIHC);
  const int tot = 262144 + 786432 * 3 + 393216;
  for (int i = blockIdx.x * blockDim.x + threadIdx.x; i < tot; i += gridDim.x * blockDim.x) {
    if (i < 262144) { Whbf[i] = f2bf(Wh[i]); }
    else if (i < 262144 + 786432) { int j = i - 262144; Whh0bf[j] = f2bf(Whh0[j]); }
    else if (i < 262144 + 2 * 786432) { int j = i - 262144 - 786432; Wih1bf[j] = f2bf(Wih1[j]); }
    else if (i < 262144 + 3 * 786432) { int j = i - 262144 - 2 * 786432; Whh1bf[j] = f2bf(Whh1[j]); }
    else {
      int j = i - 262144 - 3 * 786432;
      int r = j >> 8, e = j & 255;
      WihCbf[j] = f2bf(Wih0[(size_t)r * 384 + 128 + e]);
    }
  }
}

__global__ void k_gitok(const float* emb, const float* Wih0, const float* bih0, char* ws) {
  float* gt = (float*)(ws + OFF_GTOK);
  const int vt = blockIdx.x;
  const int tid = threadIdx.x;
  __shared__ float ev[EE];
  if (tid < EE) ev[tid] = emb[(size_t)vt * EE + tid];
  __syncthreads();
  for (int r = tid; r < 1536; r += 256) {
    float a = bih0[r];
    const float* wr = Wih0 + (size_t)r * 384;
    for (int e = 0; e < EE; ++e) a += wr[e] * ev[e];
    gt[(size_t)vt * 1536 + r] = a;
  }
}

__global__ void k_keys(const float* enc, const float* Ws, char* ws) {
  unsigned short* keys = (unsigned short*)(ws + OFF_KEYS);
  __shared__ float et[32][ED];
  const int tid = threadIdx.x;
  const int row0 = blockIdx.x * 32;
  for (int r = 0; r < 32; ++r) et[r][tid] = enc[(size_t)(row0 + r) * ED + tid];
  __syncthreads();
  for (int hhh = 0; hhh < 2; ++hhh) {
    const int h = hhh * 256 + tid;
    float acc[32];
    #pragma unroll
    for (int ll = 0; ll < 32; ++ll) acc[ll] = 0.f;
    const float4* wrow = (const float4*)(Ws + (size_t)h * ED);
    for (int e4 = 0; e4 < 64; ++e4) {
      float4 w = wrow[e4];
      #pragma unroll
      for (int ll = 0; ll < 32; ++ll) {
        acc[ll] += w.x * et[ll][e4 * 4] + w.y * et[ll][e4 * 4 + 1]
                 + w.z * et[ll][e4 * 4 + 2] + w.w * et[ll][e4 * 4 + 3];
      }
    }
    for (int ll = 0; ll < 32; ++ll)
      keys[(size_t)(row0 + ll) * HH + h] = f2bf(acc[ll]);
  }
}

__global__ void k_init(const float* enc, const float* Winit, const float* binit,
                       const float* Wh, char* ws) {
  const int b = blockIdx.x;
  const int tid = threadIdx.x; // 256
  __shared__ float pooled[ED];
  __shared__ float h1loc[HH];
  float acc = 0.f;
  for (int l = 0; l < LL; ++l) acc += enc[((size_t)b * LL + l) * ED + tid];
  pooled[tid] = acc * (1.0f / 512.0f);
  __syncthreads();
  float* h0 = (float*)(ws + OFF_H0);
  float* h1 = (float*)(ws + OFF_H1);
  for (int pass = 0; pass < 4; ++pass) {
    const int j = pass * 256 + tid;
    float a = binit[j];
    const float* wr = Winit + (size_t)j * ED;
    for (int e = 0; e < ED; ++e) a += wr[e] * pooled[e];
    const float val = tanh_fast(a);
    const int nl = j >> 9, h = j & 511;
    if (nl == 0) h0[(size_t)b * HH + h] = val;
    else { h1[(size_t)b * HH + h] = val; h1loc[h] = val; }
  }
  __syncthreads();
  unsigned short* qp = (unsigned short*)(ws + OFF_QP);
  for (int pass = 0; pass < 2; ++pass) {
    const int j = pass * 256 + tid;
    const float* wr = Wh + (size_t)j * HH;
    float a = 0.f;
    for (int k = 0; k < HH; ++k) a += wr[k] * h1loc[k];
    qp[((size_t)0 * BB + b) * HH + j] = f2bf(a);
  }
  for (int c = 1; c < 32; ++c) {
    qp[((size_t)c * BB + b) * HH + tid] = 0;
    qp[((size_t)c * BB + b) * HH + 256 + tid] = 0;
  }
  if (b == 0 && tid < 18) *(unsigned*)(ws + OFF_BAR + (size_t)tid * 64) = 0u;
}

// ---------------- main persistent decoder ----------------
__launch_bounds__(NTHR, 1)
__global__ void k_decode(char* ws, const float* enc, const int* targets,
                         const float* vvec, const float* bhh0, const float* bhh1,
                         const float* bih1, const float* Wout) {
  extern __shared__ char smem[];
  const int tid = threadIdx.x;
  const int blk = blockIdx.x;

  const unsigned short* keysg  = (const unsigned short*)(ws + OFF_KEYS);
  const unsigned short* Whbf   = (const unsigned short*)(ws + OFF_WH);
  const unsigned short* Whh0bf = (const unsigned short*)(ws + OFF_WHH0);
  const unsigned short* Wih1bf = (const unsigned short*)(ws + OFF_WIH1);
  const unsigned short* Whh1bf = (const unsigned short*)(ws + OFF_WHH1);
  const unsigned short* WihCbf = (const unsigned short*)(ws + OFF_WIHC);
  const float* gi_tok = (const float*)(ws + OFF_GTOK);
  float* h0   = (float*)(ws + OFF_H0);
  float* h1   = (float*)(ws + OFF_H1);
  float* gh0  = (float*)(ws + OFF_GH0);
  float* gh1  = (float*)(ws + OFF_GH1);
  float* ctxp = (float*)(ws + OFF_CTXP);
  float* smms = (float*)(ws + OFF_SMMS);
  unsigned short* q_part = (unsigned short*)(ws + OFF_QP);
  float* lp   = (float*)(ws + OFF_LP);
  char* barb  = ws + OFF_BAR;

  float* qb  = (float*)(smem + L_Q);
  float* vvl = (float*)(smem + L_VV);
  float* scb = (float*)(smem + L_SC);
  float* atb = (float*)(smem + L_AT);
  __shared__ float sred[8];

  // roles
  const int ab = blk >> 2, alq = blk & 3;                      // attention
  const int gmat = blk & 1, gg = (blk >> 1) & 3, gc = blk >> 3; // gh matvec
  const int pg = blk & 7, pc = blk >> 3;                       // phases B/C

  // ---------- preloads (once) ----------
  // keys -> LDS, swizzled: byte = l*1024 + ((h*2) ^ ((l&7)<<4))
  for (int idx = tid; idx < 8192; idx += NTHR) {
    const int l = idx >> 6, hs = idx & 63;
    ushort8 kv = *(const ushort8*)(keysg + ((size_t)(ab * LL + alq * 128 + l) * HH + hs * 8));
    *(ushort8*)(smem + L_KEYS + l * 1024 + ((hs * 16) ^ ((l & 7) << 4))) = kv;
  }
  vvl[tid] = vvec[tid];

  // enc slice -> 32 packed regs: thread (e=tid>>1, lh=tid&1) holds 64 l values
  uint encp[32];
  {
    const int e = tid >> 1, lh = tid & 1;
    const float* ebase = enc + ((size_t)(ab * LL + alq * 128 + lh * 64)) * ED + e;
    #pragma unroll
    for (int j = 0; j < 32; ++j) {
      float a0 = ebase[(size_t)(2 * j) * ED];
      float a1 = ebase[(size_t)(2 * j + 1) * ED];
      encp[j] = (uint)f2bf(a0) | ((uint)f2bf(a1) << 16);
    }
  }

  const int grl = tid >> 5, gks = tid & 31;   // gh threads (same as hloc/kseg)
  const int hloc = grl, kseg = gks;

  // gh weights: rows r_i = gc*48 + i*16 + grl, k in [gks*16, +16)
  uint wgh[24]; float bgh[3];
  {
    const unsigned short* Wg = gmat ? Whh1bf : Whh0bf;
    const float* bg = gmat ? bhh1 : bhh0;
    #pragma unroll
    for (int i = 0; i < 3; ++i) {
      const int r = gc * 48 + i * 16 + grl;
      bgh[i] = bg[r];
      #pragma unroll
      for (int kk = 0; kk < 8; ++kk)
        wgh[i * 8 + kk] = *(const uint*)(Wg + (size_t)r * HH + gks * 16 + kk * 2);
    }
  }
  // WihC: rows g*512 + pc*16 + hloc, k in [kseg*8, +8)
  uint wic[12];
  #pragma unroll
  for (int g = 0; g < 3; ++g)
    #pragma unroll
    for (int kk = 0; kk < 4; ++kk)
      wic[g * 4 + kk] = *(const uint*)(WihCbf + (size_t)(g * HH + pc * 16 + hloc) * ED + kseg * 8 + kk * 2);
  // Wih1: rows g*512 + pc*16 + hloc, k in [kseg*16, +16)
  uint wi1[24]; float bi1[3];
  #pragma unroll
  for (int g = 0; g < 3; ++g) {
    bi1[g] = bih1[g * HH + pc * 16 + hloc];
    #pragma unroll
    for (int kk = 0; kk < 8; ++kk)
      wi1[g * 8 + kk] = *(const uint*)(Wih1bf + (size_t)(g * HH + pc * 16 + hloc) * HH + kseg * 16 + kk * 2);
  }
  // Wh slice: row tid, cols pc*16..+16
  uint whp[8];
  #pragma unroll
  for (int i = 0; i < 8; ++i)
    whp[i] = *(const uint*)(Whbf + (size_t)tid * HH + pc * 16 + i * 2);

  __syncthreads();

  for (int t = 0; t < LL; ++t) {
    // ================= PHASE A =================
    {
      // A1: stage h (16 b for this block's gh role) as bf16 into SCR
      {
        const float* hsrc = (gmat ? h1 : h0) + (size_t)gg * 16 * HH + (size_t)tid * 16;
        float4 f0 = *(const float4*)(hsrc + 0);
        float4 f1 = *(const float4*)(hsrc + 4);
        float4 f2 = *(const float4*)(hsrc + 8);
        float4 f3 = *(const float4*)(hsrc + 12);
        ushort8 pa, pb2;
        pa[0]=f2bf(f0.x); pa[1]=f2bf(f0.y); pa[2]=f2bf(f0.z); pa[3]=f2bf(f0.w);
        pa[4]=f2bf(f1.x); pa[5]=f2bf(f1.y); pa[6]=f2bf(f1.z); pa[7]=f2bf(f1.w);
        pb2[0]=f2bf(f2.x); pb2[1]=f2bf(f2.y); pb2[2]=f2bf(f2.z); pb2[3]=f2bf(f2.w);
        pb2[4]=f2bf(f3.x); pb2[5]=f2bf(f3.y); pb2[6]=f2bf(f3.z); pb2[7]=f2bf(f3.w);
        *(ushort8*)(smem + L_SCR + tid * 32) = pa;
        *(ushort8*)(smem + L_SCR + tid * 32 + 16) = pb2;
      }
      // A2: q reduce (bf16 partials)
      {
        float qa = 0.f;
        const unsigned short* qp = q_part + (size_t)ab * HH + tid;
        #pragma unroll 8
        for (int c = 0; c < 32; ++c) qa += bfu(qp[(size_t)c * (BB * HH)]);
        qb[tid] = qa;
      }
      __syncthreads();
      // A3: scores (keys from swizzled LDS)
      {
        const int lloc = tid >> 2, hq = tid & 3;
        const char* kbase = smem + L_KEYS + lloc * 1024;
        const int xo = (lloc & 7) << 4;
        float s = 0.f;
        #pragma unroll 4
        for (int i8 = 0; i8 < 16; ++i8) {
          ushort8 kk = *(const ushort8*)(kbase + ((hq * 256 + i8 * 16) ^ xo));
          const float* qh = qb + hq * 128 + i8 * 8;
          const float* vh = vvl + hq * 128 + i8 * 8;
          #pragma unroll
          for (int j = 0; j < 8; ++j)
            s += vh[j] * tanh_fast(qh[j] + bfu(kk[j]));
        }
        s += __shfl_xor(s, 1);
        s += __shfl_xor(s, 2);
        if (hq == 0) scb[lloc] = s;
      }
      __syncthreads();
      // softmax partials over 128 scores
      {
        float x = scb[tid & 127];
        #pragma unroll
        for (int off = 32; off >= 1; off >>= 1) x = fmaxf(x, __shfl_xor(x, off));
        if ((tid & 63) == 0) sred[tid >> 6] = x;
        __syncthreads();
        float m = sred[0];
        #pragma unroll
        for (int w = 1; w < 8; ++w) m = fmaxf(m, sred[w]);
        __syncthreads();
        float e = 0.f;
        if (tid < 128) { e = exp_fast(scb[tid] - m); atb[tid] = e; }
        float s2 = e;
        #pragma unroll
        for (int off = 32; off >= 1; off >>= 1) s2 += __shfl_xor(s2, off);
        if ((tid & 63) == 0) sred[tid >> 6] = s2;
        __syncthreads();
        if (tid == 0) {
          float S = 0.f;
          #pragma unroll
          for (int w = 0; w < 8; ++w) S += sred[w];
          smms[((size_t)alq * BB + ab) * 2 + 0] = m;
          smms[((size_t)alq * BB + ab) * 2 + 1] = S;
        }
        __syncthreads();
      }
      // A4: ctx partial from enc regs
      {
        const int lh = tid & 1;
        const int e = tid >> 1;
        const float* atp = atb + lh * 64;
        float a = 0.f;
        #pragma unroll
        for (int j = 0; j < 32; ++j) {
          uint u = encp[j];
          a += atp[2 * j] * bflo(u) + atp[2 * j + 1] * bfhi(u);
        }
        a += __shfl_xor(a, 1);
        if (lh == 0) ctxp[((size_t)alq * BB + ab) * ED + e] = a;
      }
      // A5: gh matvec (weights in regs, h from SCR)
      {
        float wf[48];
        #pragma unroll
        for (int k = 0; k < 24; ++k) { wf[2 * k] = bflo(wgh[k]); wf[2 * k + 1] = bfhi(wgh[k]); }
        float* ghd = gmat ? gh1 : gh0;
        for (int b = 0; b < 16; ++b) {
          ushort8 ha = *(const ushort8*)(smem + L_SCR + b * 1024 + gks * 32);
          ushort8 hb = *(const ushort8*)(smem + L_SCR + b * 1024 + gks * 32 + 16);
          float a0 = 0.f, a1 = 0.f, a2 = 0.f;
          #pragma unroll
          for (int j = 0; j < 8; ++j) {
            const float hv = bfu(ha[j]);
            a0 += wf[j] * hv; a1 += wf[16 + j] * hv; a2 += wf[32 + j] * hv;
          }
          #pragma unroll
          for (int j = 0; j < 8; ++j) {
            const float hv = bfu(hb[j]);
            a0 += wf[8 + j] * hv; a1 += wf[24 + j] * hv; a2 += wf[40 + j] * hv;
          }
          #pragma unroll
          for (int off = 16; off >= 1; off >>= 1) {
            a0 += __shfl_xor(a0, off); a1 += __shfl_xor(a1, off); a2 += __shfl_xor(a2, off);
          }
          if (gks == 0) {
            const int bg = gg * 16 + b;
            ghd[(size_t)bg * 1536 + gc * 48 + 0 * 16 + grl] = a0 + bgh[0];
            ghd[(size_t)bg * 1536 + gc * 48 + 1 * 16 + grl] = a1 + bgh[1];
            ghd[(size_t)bg * 1536 + gc * 48 + 2 * 16 + grl] = a2 + bgh[2];
          }
        }
      }
    }
    grid_barrier(barb, (unsigned)(3 * t + 1));

    // ================= PHASE B: ctx merge + gi0 + layer0 gates =================
    {
      float* scrf = (float*)(smem + L_SCR);
      const int e2 = tid & 255, bh = tid >> 8;
      for (int it = 0; it < 4; ++it) {
        const int bloc = it * 2 + bh;
        const int b = pg * 8 + bloc;
        float mm[4], ss[4];
        #pragma unroll
        for (int p = 0; p < 4; ++p) {
          mm[p] = smms[((size_t)p * BB + b) * 2 + 0];
          ss[p] = smms[((size_t)p * BB + b) * 2 + 1];
        }
        const float M = fmaxf(fmaxf(mm[0], mm[1]), fmaxf(mm[2], mm[3]));
        float S = 0.f, acc = 0.f;
        #pragma unroll
        for (int p = 0; p < 4; ++p) {
          const float w = exp_fast(mm[p] - M);
          S += ss[p] * w;
          acc += ctxp[((size_t)p * BB + b) * ED + e2] * w;
        }
        scrf[bloc * 256 + e2] = acc / S;
      }
      __syncthreads();
      float wf[24];
      #pragma unroll
      for (int k = 0; k < 12; ++k) { wf[2 * k] = bflo(wic[k]); wf[2 * k + 1] = bfhi(wic[k]); }
      for (int b = 0; b < 8; ++b) {
        const float* cx = scrf + b * 256 + kseg * 8;
        float a0 = 0.f, a1 = 0.f, a2 = 0.f;
        #pragma unroll
        for (int j = 0; j < 8; ++j) {
          const float c = cx[j];
          a0 += wf[j] * c; a1 += wf[8 + j] * c; a2 += wf[16 + j] * c;
        }
        #pragma unroll
        for (int off = 16; off >= 1; off >>= 1) {
          a0 += __shfl_xor(a0, off); a1 += __shfl_xor(a1, off); a2 += __shfl_xor(a2, off);
        }
        if (kseg == 0) {
          const int bb = pg * 8 + b;
          const int h = pc * 16 + hloc;
          const int tok = (t == 0) ? SOS : targets[(size_t)bb * LL + t - 1];
          const float* gt = gi_tok + (size_t)tok * 1536;
          const float ir = a0 + gt[h];
          const float iz = a1 + gt[HH + h];
          const float in_ = a2 + gt[2 * HH + h];
          const float hr = gh0[(size_t)bb * 1536 + h];
          const float hz = gh0[(size_t)bb * 1536 + HH + h];
          const float hn = gh0[(size_t)bb * 1536 + 2 * HH + h];
          const float rg = sigmoid_fast(ir + hr);
          const float zg = sigmoid_fast(iz + hz);
          const float ng = tanh_fast(in_ + rg * hn);
          const float ho = h0[(size_t)bb * HH + h];
          h0[(size_t)bb * HH + h] = (1.f - zg) * ng + zg * ho;
        }
      }
    }
    grid_barrier(barb, (unsigned)(3 * t + 2));

    // ================= PHASE C: gi1 + layer1 gates + q_part + logits =========
    {
      // stage new h0 (8 b) as bf16 into SCR
      {
        const float* src = h0 + (size_t)pg * 8 * HH + (size_t)tid * 8;
        float4 f0 = *(const float4*)(src);
        float4 f1 = *(const float4*)(src + 4);
        ushort8 pa;
        pa[0]=f2bf(f0.x); pa[1]=f2bf(f0.y); pa[2]=f2bf(f0.z); pa[3]=f2bf(f0.w);
        pa[4]=f2bf(f1.x); pa[5]=f2bf(f1.y); pa[6]=f2bf(f1.z); pa[7]=f2bf(f1.w);
        *(ushort8*)(smem + L_SCR + tid * 16) = pa;
      }
      __syncthreads();
      float* h1nb = (float*)(smem + L_SCR + 8192);
      {
        float wf[48];
        #pragma unroll
        for (int k = 0; k < 24; ++k) { wf[2 * k] = bflo(wi1[k]); wf[2 * k + 1] = bfhi(wi1[k]); }
        for (int b = 0; b < 8; ++b) {
          ushort8 ha = *(const ushort8*)(smem + L_SCR + b * 1024 + kseg * 32);
          ushort8 hb = *(const ushort8*)(smem + L_SCR + b * 1024 + kseg * 32 + 16);
          float a0 = 0.f, a1 = 0.f, a2 = 0.f;
          #pragma unroll
          for (int j = 0; j < 8; ++j) {
            const float hv = bfu(ha[j]);
            a0 += wf[j] * hv; a1 += wf[16 + j] * hv; a2 += wf[32 + j] * hv;
          }
          #pragma unroll
          for (int j = 0; j < 8; ++j) {
            const float hv = bfu(hb[j]);
            a0 += wf[8 + j] * hv; a1 += wf[24 + j] * hv; a2 += wf[40 + j] * hv;
          }
          #pragma unroll
          for (int off = 16; off >= 1; off >>= 1) {
            a0 += __shfl_xor(a0, off); a1 += __shfl_xor(a1, off); a2 += __shfl_xor(a2, off);
          }
          if (kseg == 0) {
            const int bb = pg * 8 + b;
            const int h = pc * 16 + hloc;
            const float ir = a0 + bi1[0];
            const float iz = a1 + bi1[1];
            const float in_ = a2 + bi1[2];
            const float hr = gh1[(size_t)bb * 1536 + h];
            const float hz = gh1[(size_t)bb * 1536 + HH + h];
            const float hn = gh1[(size_t)bb * 1536 + 2 * HH + h];
            const float rg = sigmoid_fast(ir + hr);
            const float zg = sigmoid_fast(iz + hz);
            const float ng = tanh_fast(in_ + rg * hn);
            const float h1o = h1[(size_t)bb * HH + h];
            const float h1nv = (1.f - zg) * ng + zg * h1o;
            h1[(size_t)bb * HH + h] = h1nv;
            h1nb[b * 16 + hloc] = h1nv;
          }
        }
      }
      __syncthreads();
      // q_part for next step (bf16)
      {
        float wq[16];
        #pragma unroll
        for (int i = 0; i < 8; ++i) { wq[2 * i] = bflo(whp[i]); wq[2 * i + 1] = bfhi(whp[i]); }
        for (int b = 0; b < 8; ++b) {
          float a = 0.f;
          #pragma unroll
          for (int i = 0; i < 16; ++i) a += wq[i] * h1nb[b * 16 + i];
          q_part[((size_t)pc * BB + (pg * 8 + b)) * HH + tid] = f2bf(a);
        }
      }
      // logit partials
      if (tid < 32) {
        const int b2 = tid >> 2, v = tid & 3;
        float a = 0.f;
        #pragma unroll
        for (int i = 0; i < 16; ++i)
          a += Wout[(size_t)v * HH + pc * 16 + i] * h1nb[b2 * 16 + i];
        lp[((size_t)t * 32 + pc) * (BB * VV) + (size_t)(pg * 8 + b2) * VV + v] = a;
      }
    }
    grid_barrier(barb, (unsigned)(3 * t + 3));
  }
}

// sum logit partials -> out
__global__ void k_lsum(const char* ws, const float* bout, float* out) {
  const float* lp = (const float*)(ws + OFF_LP);
  const int i = blockIdx.x * 256 + threadIdx.x;
  if (i >= BB * LL * VV) return;
  const int v = i & 3, t = (i >> 2) & 511, b = i >> 11;
  float a = bout[v];
  for (int c = 0; c < 32; ++c)
    a += lp[((size_t)t * 32 + c) * (BB * VV) + (size_t)b * VV + v];
  out[i] = a;
}

// ---------------- launch ----------------
extern "C" void kernel_launch(void* const* d_in, const int* in_sizes, int n_in,
                              void* d_out, int out_size, void* d_ws, size_t ws_size,
                              hipStream_t stream) {
  char* ws = (char*)d_ws;
  const float* enc     = (const float*)d_in[0];
  const int*   targets = (const int*)d_in[1];
  const float* emb   = (const float*)d_in[4];
  const float* Wh    = (const float*)d_in[5];
  const float* Ws    = (const float*)d_in[6];
  const float* vvec  = (const float*)d_in[7];
  const float* Wih0  = (const float*)d_in[8];
  const float* Whh0  = (const float*)d_in[9];
  const float* bih0  = (const float*)d_in[10];
  const float* bhh0  = (const float*)d_in[11];
  const float* Wih1  = (const float*)d_in[12];
  const float* Whh1  = (const float*)d_in[13];
  const float* bih1  = (const float*)d_in[14];
  const float* bhh1  = (const float*)d_in[15];
  const float* Wout  = (const float*)d_in[16];
  const float* bout  = (const float*)d_in[17];
  const float* Winit = (const float*)d_in[18];
  const float* binit = (const float*)d_in[19];

  k_prep <<<1024, 256, 0, stream>>>(Wh, Whh0, Wih0, Wih1, Whh1, ws);
  k_gitok<<<6,    256, 0, stream>>>(emb, Wih0, bih0, ws);
  k_keys <<<1024, 256, 0, stream>>>(enc, Ws, ws);
  k_init <<<64,   256, 0, stream>>>(enc, Winit, binit, Wh, ws);

  // allow >64KB dynamic LDS (idempotent; ignore errors)
  (void)hipFuncSetAttribute((const void*)k_decode,
                            hipFuncAttributeMaxDynamicSharedMemorySize, L_TOT);

  {
    void* kws = (void*)ws;
    void* ken = (void*)enc;
    void* ktg = (void*)targets;
    void* kvv = (void*)vvec;
    void* kb0 = (void*)bhh0;
    void* kb1 = (void*)bhh1;
    void* kbi = (void*)bih1;
    void* kwo = (void*)Wout;
    void* args[] = { &kws, &ken, &ktg, &kvv, &kb0, &kb1, &kbi, &kwo };
    hipError_t ce = hipLaunchCooperativeKernel((const void*)k_decode, dim3(NBLK), dim3(NTHR),
                                               args, L_TOT, stream);
    if (ce != hipSuccess) {
      k_decode<<<dim3(NBLK), dim3(NTHR), L_TOT, stream>>>(ws, enc, targets, vvec,
                                                          bhh0, bhh1, bih1, Wout);
    }
  }

  k_lsum<<<512, 256, 0, stream>>>(ws, bout, (float*)d_out);
}

// Round 3
// 55129.095 us; speedup vs baseline: 1.5418x; 1.5418x over previous
//
#include <hip/hip_runtime.h>
#include <cstdint>
#include <cstddef>

// GRU decoder w/ Bahdanau attention, B=64 L=512 E=128 H=512 ENC=256 V=4 NL=2.
// R3: same structure as R2 (keys in LDS, weights/enc in regs, 3 grid barriers
// per step) but FENCE-FREE coherence: all cross-block state via relaxed
// agent-scope atomics (sc0/sc1 cache-bypass, no buffer_inv/wbl2 storms);
// barrier release = s_waitcnt vmcnt(0) + relaxed flag; relaxed spin.

#define BB   64
#define LL   512
#define EE   128
#define HH   512
#define ED   256
#define VV   4
#define SOS  4

#define NBLK 256
#define NTHR 512

typedef unsigned short ushort8 __attribute__((ext_vector_type(8)));
typedef unsigned int uint;

// ---------------- ws layout (bytes) ----------------
static const size_t OFF_KEYS = 0;          // ushort [B][L][H]    33,554,432
static const size_t OFF_WH   = 50331648;   // ushort [H][H]          524,288
static const size_t OFF_WHH0 = 50855936;   // ushort [3H][H]       1,572,864
static const size_t OFF_WIH1 = 52428800;   // ushort [3H][H]       1,572,864
static const size_t OFF_WHH1 = 54001664;   // ushort [3H][H]       1,572,864
static const size_t OFF_WIHC = 55574528;   // ushort [3H][ED]        786,432
static const size_t OFF_GTOK = 56360960;   // float  [6][3H]          36,864
static const size_t OFF_H0   = 56397824;   // float  [B][H]
static const size_t OFF_H1   = 56528896;   // float  [B][H]
static const size_t OFF_GH0  = 56659968;   // float  [B][3H]
static const size_t OFF_GH1  = 57053184;   // float  [B][3H]
static const size_t OFF_CTXP = 57446400;   // float  [4][B][ED]
static const size_t OFF_SMMS = 57708544;   // float  [4][B][2]
static const size_t OFF_QP   = 57710592;   // float  [32][B][H]    4,194,304
static const size_t OFF_LP   = 61904896;   // float  [L][32][B*V] 16,777,216
static const size_t OFF_BAR  = 78682112;   // 18 x 64B barrier lines

// ---------------- dynamic LDS layout (bytes) ----------------
#define L_KEYS 0          // 131072 : swizzled keys [128][512] bf16
#define L_Q    131072     // 2048   : q[512] f32
#define L_VV   133120     // 2048   : v[512] f32
#define L_SC   135168     // 512    : scores[128]
#define L_AT   135680     // 512    : attn[128]
#define L_SCR  136192     // 16384  : phase scratch
#define L_TOT  152576

// ---------------- helpers ----------------
__device__ __forceinline__ float bfu(unsigned short u) {
  return __uint_as_float(((unsigned)u) << 16);
}
__device__ __forceinline__ float bflo(uint u) { return __uint_as_float(u << 16); }
__device__ __forceinline__ float bfhi(uint u) { return __uint_as_float(u & 0xffff0000u); }
__device__ __forceinline__ unsigned short f2bf(float f) {
  unsigned u = __float_as_uint(f);
  unsigned r = 0x7FFFu + ((u >> 16) & 1u);
  return (unsigned short)((u + r) >> 16);
}
__device__ __forceinline__ float tanh_fast(float x) {
  x = __builtin_amdgcn_fmed3f(x, -10.f, 10.f);
  float t = __builtin_amdgcn_exp2f(x * 2.8853900817779268f); // e^{2x}
  return (t - 1.f) * __builtin_amdgcn_rcpf(t + 1.f);
}
__device__ __forceinline__ float sigmoid_fast(float x) {
  x = __builtin_amdgcn_fmed3f(x, -30.f, 30.f);
  float t = __builtin_amdgcn_exp2f(x * -1.4426950408889634f);
  return __builtin_amdgcn_rcpf(1.f + t);
}
__device__ __forceinline__ float exp_fast(float x) {
  return __builtin_amdgcn_exp2f(x * 1.4426950408889634f);
}

// cache-bypassing (coherence-point) scalar accessors — NO fences attached.
__device__ __forceinline__ float gload(const float* p) {
  return __hip_atomic_load((const float*)p, __ATOMIC_RELAXED, __HIP_MEMORY_SCOPE_AGENT);
}
__device__ __forceinline__ void gstore(float* p, float v) {
  __hip_atomic_store(p, v, __ATOMIC_RELAXED, __HIP_MEMORY_SCOPE_AGENT);
}

// two-level grid barrier, fence-free: release = vmcnt(0) drain before arrival
// fetch_add (all state stores are sc0/sc1 so drain => globally visible);
// spin with RELAXED loads (no buffer_inv).
__device__ __forceinline__ void grid_barrier(char* barbase, unsigned gen) {
  __syncthreads();
  if (threadIdx.x == 0) {
    unsigned* grpc = (unsigned*)(barbase + (size_t)(blockIdx.x >> 4) * 64);
    unsigned* mstc = (unsigned*)(barbase + 16 * 64);
    unsigned* rel  = (unsigned*)(barbase + 17 * 64);
    asm volatile("s_waitcnt vmcnt(0)" ::: "memory");
    bool last = false;
    unsigned p = __hip_atomic_fetch_add(grpc, 1u, __ATOMIC_RELAXED, __HIP_MEMORY_SCOPE_AGENT);
    if (p == 15u) {
      unsigned q = __hip_atomic_fetch_add(mstc, 1u, __ATOMIC_RELAXED, __HIP_MEMORY_SCOPE_AGENT);
      if (q == 15u) {
        #pragma unroll
        for (int g = 0; g < 16; ++g)
          __hip_atomic_store((unsigned*)(barbase + (size_t)g * 64), 0u, __ATOMIC_RELAXED, __HIP_MEMORY_SCOPE_AGENT);
        __hip_atomic_store(mstc, 0u, __ATOMIC_RELAXED, __HIP_MEMORY_SCOPE_AGENT);
        asm volatile("s_waitcnt vmcnt(0)" ::: "memory");
        __hip_atomic_store(rel, gen, __ATOMIC_RELAXED, __HIP_MEMORY_SCOPE_AGENT);
        last = true;
      }
    }
    if (!last) {
      while (__hip_atomic_load(rel, __ATOMIC_RELAXED, __HIP_MEMORY_SCOPE_AGENT) < gen)
        __builtin_amdgcn_s_sleep(1);
    }
    asm volatile("" ::: "memory");
  }
  __syncthreads();
}

// ---------------- precompute kernels ----------------

__global__ void k_prep(const float* Wh, const float* Whh0, const float* Wih0,
                       const float* Wih1, const float* Whh1, char* ws) {
  unsigned short* Whbf   = (unsigned short*)(ws + OFF_WH);
  unsigned short* Whh0bf = (unsigned short*)(ws + OFF_WHH0);
  unsigned short* Wih1bf = (unsigned short*)(ws + OFF_WIH1);
  unsigned short* Whh1bf = (unsigned short*)(ws + OFF_WHH1);
  unsigned short* WihCbf = (unsigned short*)(ws + OFF_WIHC);
  const int tot = 262144 + 786432 * 3 + 393216;
  for (int i = blockIdx.x * blockDim.x + threadIdx.x; i < tot; i += gridDim.x * blockDim.x) {
    if (i < 262144) { Whbf[i] = f2bf(Wh[i]); }
    else if (i < 262144 + 786432) { int j = i - 262144; Whh0bf[j] = f2bf(Whh0[j]); }
    else if (i < 262144 + 2 * 786432) { int j = i - 262144 - 786432; Wih1bf[j] = f2bf(Wih1[j]); }
    else if (i < 262144 + 3 * 786432) { int j = i - 262144 - 2 * 786432; Whh1bf[j] = f2bf(Whh1[j]); }
    else {
      int j = i - 262144 - 3 * 786432;
      int r = j >> 8, e = j & 255;
      WihCbf[j] = f2bf(Wih0[(size_t)r * 384 + 128 + e]);
    }
  }
}

__global__ void k_gitok(const float* emb, const float* Wih0, const float* bih0, char* ws) {
  float* gt = (float*)(ws + OFF_GTOK);
  const int vt = blockIdx.x;
  const int tid = threadIdx.x;
  __shared__ float ev[EE];
  if (tid < EE) ev[tid] = emb[(size_t)vt * EE + tid];
  __syncthreads();
  for (int r = tid; r < 1536; r += 256) {
    float a = bih0[r];
    const float* wr = Wih0 + (size_t)r * 384;
    for (int e = 0; e < EE; ++e) a += wr[e] * ev[e];
    gt[(size_t)vt * 1536 + r] = a;
  }
}

__global__ void k_keys(const float* enc, const float* Ws, char* ws) {
  unsigned short* keys = (unsigned short*)(ws + OFF_KEYS);
  __shared__ float et[32][ED];
  const int tid = threadIdx.x;
  const int row0 = blockIdx.x * 32;
  for (int r = 0; r < 32; ++r) et[r][tid] = enc[(size_t)(row0 + r) * ED + tid];
  __syncthreads();
  for (int hhh = 0; hhh < 2; ++hhh) {
    const int h = hhh * 256 + tid;
    float acc[32];
    #pragma unroll
    for (int ll = 0; ll < 32; ++ll) acc[ll] = 0.f;
    const float4* wrow = (const float4*)(Ws + (size_t)h * ED);
    for (int e4 = 0; e4 < 64; ++e4) {
      float4 w = wrow[e4];
      #pragma unroll
      for (int ll = 0; ll < 32; ++ll) {
        acc[ll] += w.x * et[ll][e4 * 4] + w.y * et[ll][e4 * 4 + 1]
                 + w.z * et[ll][e4 * 4 + 2] + w.w * et[ll][e4 * 4 + 3];
      }
    }
    for (int ll = 0; ll < 32; ++ll)
      keys[(size_t)(row0 + ll) * HH + h] = f2bf(acc[ll]);
  }
}

__global__ void k_init(const float* enc, const float* Winit, const float* binit,
                       const float* Wh, char* ws) {
  const int b = blockIdx.x;
  const int tid = threadIdx.x; // 256
  __shared__ float pooled[ED];
  __shared__ float h1loc[HH];
  float acc = 0.f;
  for (int l = 0; l < LL; ++l) acc += enc[((size_t)b * LL + l) * ED + tid];
  pooled[tid] = acc * (1.0f / 512.0f);
  __syncthreads();
  float* h0 = (float*)(ws + OFF_H0);
  float* h1 = (float*)(ws + OFF_H1);
  for (int pass = 0; pass < 4; ++pass) {
    const int j = pass * 256 + tid;
    float a = binit[j];
    const float* wr = Winit + (size_t)j * ED;
    for (int e = 0; e < ED; ++e) a += wr[e] * pooled[e];
    const float val = tanh_fast(a);
    const int nl = j >> 9, h = j & 511;
    if (nl == 0) h0[(size_t)b * HH + h] = val;
    else { h1[(size_t)b * HH + h] = val; h1loc[h] = val; }
  }
  __syncthreads();
  float* qp = (float*)(ws + OFF_QP);
  for (int pass = 0; pass < 2; ++pass) {
    const int j = pass * 256 + tid;
    const float* wr = Wh + (size_t)j * HH;
    float a = 0.f;
    for (int k = 0; k < HH; ++k) a += wr[k] * h1loc[k];
    qp[((size_t)0 * BB + b) * HH + j] = a;
  }
  for (int c = 1; c < 32; ++c) {
    qp[((size_t)c * BB + b) * HH + tid] = 0.f;
    qp[((size_t)c * BB + b) * HH + 256 + tid] = 0.f;
  }
  if (b == 0 && tid < 18) *(unsigned*)(ws + OFF_BAR + (size_t)tid * 64) = 0u;
}

// ---------------- main persistent decoder ----------------
__launch_bounds__(NTHR, 1)
__global__ void k_decode(char* ws, const float* enc, const int* targets,
                         const float* vvec, const float* bhh0, const float* bhh1,
                         const float* bih1, const float* Wout) {
  extern __shared__ char smem[];
  const int tid = threadIdx.x;
  const int blk = blockIdx.x;

  const unsigned short* keysg  = (const unsigned short*)(ws + OFF_KEYS);
  const unsigned short* Whbf   = (const unsigned short*)(ws + OFF_WH);
  const unsigned short* Whh0bf = (const unsigned short*)(ws + OFF_WHH0);
  const unsigned short* Wih1bf = (const unsigned short*)(ws + OFF_WIH1);
  const unsigned short* Whh1bf = (const unsigned short*)(ws + OFF_WHH1);
  const unsigned short* WihCbf = (const unsigned short*)(ws + OFF_WIHC);
  const float* gi_tok = (const float*)(ws + OFF_GTOK);
  float* h0   = (float*)(ws + OFF_H0);
  float* h1   = (float*)(ws + OFF_H1);
  float* gh0  = (float*)(ws + OFF_GH0);
  float* gh1  = (float*)(ws + OFF_GH1);
  float* ctxp = (float*)(ws + OFF_CTXP);
  float* smms = (float*)(ws + OFF_SMMS);
  float* q_part = (float*)(ws + OFF_QP);
  float* lp   = (float*)(ws + OFF_LP);
  char* barb  = ws + OFF_BAR;

  float* qb  = (float*)(smem + L_Q);
  float* vvl = (float*)(smem + L_VV);
  float* scb = (float*)(smem + L_SC);
  float* atb = (float*)(smem + L_AT);
  __shared__ float sred[8];

  // roles
  const int ab = blk >> 2, alq = blk & 3;                      // attention
  const int gmat = blk & 1, gg = (blk >> 1) & 3, gc = blk >> 3; // gh matvec
  const int pg = blk & 7, pc = blk >> 3;                       // phases B/C

  // ---------- preloads (once) ----------
  for (int idx = tid; idx < 8192; idx += NTHR) {
    const int l = idx >> 6, hs = idx & 63;
    ushort8 kv = *(const ushort8*)(keysg + ((size_t)(ab * LL + alq * 128 + l) * HH + hs * 8));
    *(ushort8*)(smem + L_KEYS + l * 1024 + ((hs * 16) ^ ((l & 7) << 4))) = kv;
  }
  vvl[tid] = vvec[tid];

  // enc slice -> 32 packed regs
  uint encp[32];
  {
    const int e = tid >> 1, lh = tid & 1;
    const float* ebase = enc + ((size_t)(ab * LL + alq * 128 + lh * 64)) * ED + e;
    #pragma unroll
    for (int j = 0; j < 32; ++j) {
      float a0 = ebase[(size_t)(2 * j) * ED];
      float a1 = ebase[(size_t)(2 * j + 1) * ED];
      encp[j] = (uint)f2bf(a0) | ((uint)f2bf(a1) << 16);
    }
  }

  const int grl = tid >> 5, gks = tid & 31;
  const int hloc = grl, kseg = gks;

  uint wgh[24]; float bgh[3];
  {
    const unsigned short* Wg = gmat ? Whh1bf : Whh0bf;
    const float* bg = gmat ? bhh1 : bhh0;
    #pragma unroll
    for (int i = 0; i < 3; ++i) {
      const int r = gc * 48 + i * 16 + grl;
      bgh[i] = bg[r];
      #pragma unroll
      for (int kk = 0; kk < 8; ++kk)
        wgh[i * 8 + kk] = *(const uint*)(Wg + (size_t)r * HH + gks * 16 + kk * 2);
    }
  }
  uint wic[12];
  #pragma unroll
  for (int g = 0; g < 3; ++g)
    #pragma unroll
    for (int kk = 0; kk < 4; ++kk)
      wic[g * 4 + kk] = *(const uint*)(WihCbf + (size_t)(g * HH + pc * 16 + hloc) * ED + kseg * 8 + kk * 2);
  uint wi1[24]; float bi1[3];
  #pragma unroll
  for (int g = 0; g < 3; ++g) {
    bi1[g] = bih1[g * HH + pc * 16 + hloc];
    #pragma unroll
    for (int kk = 0; kk < 8; ++kk)
      wi1[g * 8 + kk] = *(const uint*)(Wih1bf + (size_t)(g * HH + pc * 16 + hloc) * HH + kseg * 16 + kk * 2);
  }
  uint whp[8];
  #pragma unroll
  for (int i = 0; i < 8; ++i)
    whp[i] = *(const uint*)(Whbf + (size_t)tid * HH + pc * 16 + i * 2);

  __syncthreads();

  for (int t = 0; t < LL; ++t) {
    // ================= PHASE A =================
    {
      // A1: stage h (16 b for gh role) as bf16 into SCR — sc01 scalar loads
      {
        const float* hsrc = (gmat ? h1 : h0) + (size_t)gg * 16 * HH + (size_t)tid * 16;
        float hv[16];
        #pragma unroll
        for (int i = 0; i < 16; ++i) hv[i] = gload(hsrc + i);
        ushort8 pa, pb2;
        #pragma unroll
        for (int i = 0; i < 8; ++i) pa[i] = f2bf(hv[i]);
        #pragma unroll
        for (int i = 0; i < 8; ++i) pb2[i] = f2bf(hv[8 + i]);
        *(ushort8*)(smem + L_SCR + tid * 32) = pa;
        *(ushort8*)(smem + L_SCR + tid * 32 + 16) = pb2;
      }
      // A2: q reduce
      {
        float qa = 0.f;
        const float* qp = q_part + (size_t)ab * HH + tid;
        #pragma unroll 8
        for (int c = 0; c < 32; ++c) qa += gload(qp + (size_t)c * (BB * HH));
        qb[tid] = qa;
      }
      __syncthreads();
      // A3: scores (keys from swizzled LDS)
      {
        const int lloc = tid >> 2, hq = tid & 3;
        const char* kbase = smem + L_KEYS + lloc * 1024;
        const int xo = (lloc & 7) << 4;
        float s = 0.f;
        #pragma unroll 4
        for (int i8 = 0; i8 < 16; ++i8) {
          ushort8 kk = *(const ushort8*)(kbase + ((hq * 256 + i8 * 16) ^ xo));
          const float* qh = qb + hq * 128 + i8 * 8;
          const float* vh = vvl + hq * 128 + i8 * 8;
          #pragma unroll
          for (int j = 0; j < 8; ++j)
            s += vh[j] * tanh_fast(qh[j] + bfu(kk[j]));
        }
        s += __shfl_xor(s, 1);
        s += __shfl_xor(s, 2);
        if (hq == 0) scb[lloc] = s;
      }
      __syncthreads();
      // softmax partials over 128 scores
      {
        float x = scb[tid & 127];
        #pragma unroll
        for (int off = 32; off >= 1; off >>= 1) x = fmaxf(x, __shfl_xor(x, off));
        if ((tid & 63) == 0) sred[tid >> 6] = x;
        __syncthreads();
        float m = sred[0];
        #pragma unroll
        for (int w = 1; w < 8; ++w) m = fmaxf(m, sred[w]);
        __syncthreads();
        float e = 0.f;
        if (tid < 128) { e = exp_fast(scb[tid] - m); atb[tid] = e; }
        float s2 = e;
        #pragma unroll
        for (int off = 32; off >= 1; off >>= 1) s2 += __shfl_xor(s2, off);
        if ((tid & 63) == 0) sred[tid >> 6] = s2;
        __syncthreads();
        if (tid == 0) {
          float S = 0.f;
          #pragma unroll
          for (int w = 0; w < 8; ++w) S += sred[w];
          gstore(&smms[((size_t)alq * BB + ab) * 2 + 0], m);
          gstore(&smms[((size_t)alq * BB + ab) * 2 + 1], S);
        }
        __syncthreads();
      }
      // A4: ctx partial from enc regs
      {
        const int lh = tid & 1;
        const int e = tid >> 1;
        const float* atp = atb + lh * 64;
        float a = 0.f;
        #pragma unroll
        for (int j = 0; j < 32; ++j) {
          uint u = encp[j];
          a += atp[2 * j] * bflo(u) + atp[2 * j + 1] * bfhi(u);
        }
        a += __shfl_xor(a, 1);
        if (lh == 0) gstore(&ctxp[((size_t)alq * BB + ab) * ED + e], a);
      }
      // A5: gh matvec (weights in regs, h from SCR)
      {
        float wf[48];
        #pragma unroll
        for (int k = 0; k < 24; ++k) { wf[2 * k] = bflo(wgh[k]); wf[2 * k + 1] = bfhi(wgh[k]); }
        float* ghd = gmat ? gh1 : gh0;
        for (int b = 0; b < 16; ++b) {
          ushort8 ha = *(const ushort8*)(smem + L_SCR + b * 1024 + gks * 32);
          ushort8 hb = *(const ushort8*)(smem + L_SCR + b * 1024 + gks * 32 + 16);
          float a0 = 0.f, a1 = 0.f, a2 = 0.f;
          #pragma unroll
          for (int j = 0; j < 8; ++j) {
            const float hv = bfu(ha[j]);
            a0 += wf[j] * hv; a1 += wf[16 + j] * hv; a2 += wf[32 + j] * hv;
          }
          #pragma unroll
          for (int j = 0; j < 8; ++j) {
            const float hv = bfu(hb[j]);
            a0 += wf[8 + j] * hv; a1 += wf[24 + j] * hv; a2 += wf[40 + j] * hv;
          }
          #pragma unroll
          for (int off = 16; off >= 1; off >>= 1) {
            a0 += __shfl_xor(a0, off); a1 += __shfl_xor(a1, off); a2 += __shfl_xor(a2, off);
          }
          if (gks == 0) {
            const int bg = gg * 16 + b;
            gstore(&ghd[(size_t)bg * 1536 + gc * 48 + 0 * 16 + grl], a0 + bgh[0]);
            gstore(&ghd[(size_t)bg * 1536 + gc * 48 + 1 * 16 + grl], a1 + bgh[1]);
            gstore(&ghd[(size_t)bg * 1536 + gc * 48 + 2 * 16 + grl], a2 + bgh[2]);
          }
        }
      }
    }
    grid_barrier(barb, (unsigned)(3 * t + 1));

    // ================= PHASE B: ctx merge + gi0 + layer0 gates =================
    {
      float* scrf = (float*)(smem + L_SCR);
      const int e2 = tid & 255, bh = tid >> 8;
      for (int it = 0; it < 4; ++it) {
        const int bloc = it * 2 + bh;
        const int b = pg * 8 + bloc;
        float mm[4], ss[4];
        #pragma unroll
        for (int p = 0; p < 4; ++p) {
          mm[p] = gload(&smms[((size_t)p * BB + b) * 2 + 0]);
          ss[p] = gload(&smms[((size_t)p * BB + b) * 2 + 1]);
        }
        const float M = fmaxf(fmaxf(mm[0], mm[1]), fmaxf(mm[2], mm[3]));
        float S = 0.f, acc = 0.f;
        #pragma unroll
        for (int p = 0; p < 4; ++p) {
          const float w = exp_fast(mm[p] - M);
          S += ss[p] * w;
          acc += gload(&ctxp[((size_t)p * BB + b) * ED + e2]) * w;
        }
        scrf[bloc * 256 + e2] = acc / S;
      }
      __syncthreads();
      float wf[24];
      #pragma unroll
      for (int k = 0; k < 12; ++k) { wf[2 * k] = bflo(wic[k]); wf[2 * k + 1] = bfhi(wic[k]); }
      for (int b = 0; b < 8; ++b) {
        const float* cx = scrf + b * 256 + kseg * 8;
        float a0 = 0.f, a1 = 0.f, a2 = 0.f;
        #pragma unroll
        for (int j = 0; j < 8; ++j) {
          const float c = cx[j];
          a0 += wf[j] * c; a1 += wf[8 + j] * c; a2 += wf[16 + j] * c;
        }
        #pragma unroll
        for (int off = 16; off >= 1; off >>= 1) {
          a0 += __shfl_xor(a0, off); a1 += __shfl_xor(a1, off); a2 += __shfl_xor(a2, off);
        }
        if (kseg == 0) {
          const int bb = pg * 8 + b;
          const int h = pc * 16 + hloc;
          const int tok = (t == 0) ? SOS : targets[(size_t)bb * LL + t - 1];
          const float* gt = gi_tok + (size_t)tok * 1536;
          const float ir = a0 + gt[h];
          const float iz = a1 + gt[HH + h];
          const float in_ = a2 + gt[2 * HH + h];
          const float hr = gload(&gh0[(size_t)bb * 1536 + h]);
          const float hz = gload(&gh0[(size_t)bb * 1536 + HH + h]);
          const float hn = gload(&gh0[(size_t)bb * 1536 + 2 * HH + h]);
          const float rg = sigmoid_fast(ir + hr);
          const float zg = sigmoid_fast(iz + hz);
          const float ng = tanh_fast(in_ + rg * hn);
          const float ho = gload(&h0[(size_t)bb * HH + h]);
          gstore(&h0[(size_t)bb * HH + h], (1.f - zg) * ng + zg * ho);
        }
      }
    }
    grid_barrier(barb, (unsigned)(3 * t + 2));

    // ================= PHASE C: gi1 + layer1 gates + q_part + logits =========
    {
      {
        const float* src = h0 + (size_t)pg * 8 * HH + (size_t)tid * 8;
        float hv[8];
        #pragma unroll
        for (int i = 0; i < 8; ++i) hv[i] = gload(src + i);
        ushort8 pa;
        #pragma unroll
        for (int i = 0; i < 8; ++i) pa[i] = f2bf(hv[i]);
        *(ushort8*)(smem + L_SCR + tid * 16) = pa;
      }
      __syncthreads();
      float* h1nb = (float*)(smem + L_SCR + 8192);
      {
        float wf[48];
        #pragma unroll
        for (int k = 0; k < 24; ++k) { wf[2 * k] = bflo(wi1[k]); wf[2 * k + 1] = bfhi(wi1[k]); }
        for (int b = 0; b < 8; ++b) {
          ushort8 ha = *(const ushort8*)(smem + L_SCR + b * 1024 + kseg * 32);
          ushort8 hb = *(const ushort8*)(smem + L_SCR + b * 1024 + kseg * 32 + 16);
          float a0 = 0.f, a1 = 0.f, a2 = 0.f;
          #pragma unroll
          for (int j = 0; j < 8; ++j) {
            const float hv = bfu(ha[j]);
            a0 += wf[j] * hv; a1 += wf[16 + j] * hv; a2 += wf[32 + j] * hv;
          }
          #pragma unroll
          for (int j = 0; j < 8; ++j) {
            const float hv = bfu(hb[j]);
            a0 += wf[8 + j] * hv; a1 += wf[24 + j] * hv; a2 += wf[40 + j] * hv;
          }
          #pragma unroll
          for (int off = 16; off >= 1; off >>= 1) {
            a0 += __shfl_xor(a0, off); a1 += __shfl_xor(a1, off); a2 += __shfl_xor(a2, off);
          }
          if (kseg == 0) {
            const int bb = pg * 8 + b;
            const int h = pc * 16 + hloc;
            const float ir = a0 + bi1[0];
            const float iz = a1 + bi1[1];
            const float in_ = a2 + bi1[2];
            const float hr = gload(&gh1[(size_t)bb * 1536 + h]);
            const float hz = gload(&gh1[(size_t)bb * 1536 + HH + h]);
            const float hn = gload(&gh1[(size_t)bb * 1536 + 2 * HH + h]);
            const float rg = sigmoid_fast(ir + hr);
            const float zg = sigmoid_fast(iz + hz);
            const float ng = tanh_fast(in_ + rg * hn);
            const float h1o = gload(&h1[(size_t)bb * HH + h]);
            const float h1nv = (1.f - zg) * ng + zg * h1o;
            gstore(&h1[(size_t)bb * HH + h], h1nv);
            h1nb[b * 16 + hloc] = h1nv;
          }
        }
      }
      __syncthreads();
      // q_part for next step (f32, sc01 stores)
      {
        float wq[16];
        #pragma unroll
        for (int i = 0; i < 8; ++i) { wq[2 * i] = bflo(whp[i]); wq[2 * i + 1] = bfhi(whp[i]); }
        for (int b = 0; b < 8; ++b) {
          float a = 0.f;
          #pragma unroll
          for (int i = 0; i < 16; ++i) a += wq[i] * h1nb[b * 16 + i];
          gstore(&q_part[((size_t)pc * BB + (pg * 8 + b)) * HH + tid], a);
        }
      }
      // logit partials (read only after kernel end — normal stores)
      if (tid < 32) {
        const int b2 = tid >> 2, v = tid & 3;
        float a = 0.f;
        #pragma unroll
        for (int i = 0; i < 16; ++i)
          a += Wout[(size_t)v * HH + pc * 16 + i] * h1nb[b2 * 16 + i];
        lp[((size_t)t * 32 + pc) * (BB * VV) + (size_t)(pg * 8 + b2) * VV + v] = a;
      }
    }
    grid_barrier(barb, (unsigned)(3 * t + 3));
  }
}

// sum logit partials -> out
__global__ void k_lsum(const char* ws, const float* bout, float* out) {
  const float* lp = (const float*)(ws + OFF_LP);
  const int i = blockIdx.x * 256 + threadIdx.x;
  if (i >= BB * LL * VV) return;
  const int v = i & 3, t = (i >> 2) & 511, b = i >> 11;
  float a = bout[v];
  for (int c = 0; c < 32; ++c)
    a += lp[((size_t)t * 32 + c) * (BB * VV) + (size_t)b * VV + v];
  out[i] = a;
}

// ---------------- launch ----------------
extern "C" void kernel_launch(void* const* d_in, const int* in_sizes, int n_in,
                              void* d_out, int out_size, void* d_ws, size_t ws_size,
                              hipStream_t stream) {
  char* ws = (char*)d_ws;
  const float* enc     = (const float*)d_in[0];
  const int*   targets = (const int*)d_in[1];
  const float* emb   = (const float*)d_in[4];
  const float* Wh    = (const float*)d_in[5];
  const float* Ws    = (const float*)d_in[6];
  const float* vvec  = (const float*)d_in[7];
  const float* Wih0  = (const float*)d_in[8];
  const float* Whh0  = (const float*)d_in[9];
  const float* bih0  = (const float*)d_in[10];
  const float* bhh0  = (const float*)d_in[11];
  const float* Wih1  = (const float*)d_in[12];
  const float* Whh1  = (const float*)d_in[13];
  const float* bih1  = (const float*)d_in[14];
  const float* bhh1  = (const float*)d_in[15];
  const float* Wout  = (const float*)d_in[16];
  const float* bout  = (const float*)d_in[17];
  const float* Winit = (const float*)d_in[18];
  const float* binit = (const float*)d_in[19];

  k_prep <<<1024, 256, 0, stream>>>(Wh, Whh0, Wih0, Wih1, Whh1, ws);
  k_gitok<<<6,    256, 0, stream>>>(emb, Wih0, bih0, ws);
  k_keys <<<1024, 256, 0, stream>>>(enc, Ws, ws);
  k_init <<<64,   256, 0, stream>>>(enc, Winit, binit, Wh, ws);

  (void)hipFuncSetAttribute((const void*)k_decode,
                            hipFuncAttributeMaxDynamicSharedMemorySize, L_TOT);

  {
    void* kws = (void*)ws;
    void* ken = (void*)enc;
    void* ktg = (void*)targets;
    void* kvv = (void*)vvec;
    void* kb0 = (void*)bhh0;
    void* kb1 = (void*)bhh1;
    void* kbi = (void*)bih1;
    void* kwo = (void*)Wout;
    void* args[] = { &kws, &ken, &ktg, &kvv, &kb0, &kb1, &kbi, &kwo };
    hipError_t ce = hipLaunchCooperativeKernel((const void*)k_decode, dim3(NBLK), dim3(NTHR),
                                               args, L_TOT, stream);
    if (ce != hipSuccess) {
      k_decode<<<dim3(NBLK), dim3(NTHR), L_TOT, stream>>>(ws, enc, targets, vvec,
                                                          bhh0, bhh1, bih1, Wout);
    }
  }

  k_lsum<<<512, 256, 0, stream>>>(ws, bout, (float*)d_out);
}

// Round 5
// 53484.406 us; speedup vs baseline: 1.5892x; 1.0308x over previous
//
#include <hip/hip_runtime.h>
#include <cstdint>
#include <cstddef>

// GRU decoder w/ Bahdanau attention, B=64 L=512 E=128 H=512 ENC=256 V=4 NL=2.
// R5: quad-local persistent kernel (64 quads x 4 blocks); block (b,j) owns
// attention L-quarter j (keys in LDS) and h-slice [j*128,+128) of both GRU
// layers. FIXES vs R4: (1) pre-loop publishes initial h1 slice (t=0 read
// poison before), (2) all cross-block exchanges f32 (QQ/CTXP/H0Q/H1Q),
// (3) parallel logit partials. Sync = 3 quad flag-barriers/step
// (vmcnt-drain release + relaxed spin; no L2-invalidating fences anywhere).

#define BB   64
#define LL   512
#define EE   128
#define HH   512
#define ED   256
#define VV   4
#define SOS  4

#define NBLK 256
#define NTHR 512

typedef unsigned short ushort8 __attribute__((ext_vector_type(8)));
typedef unsigned int uint;

// ---------------- ws layout (bytes) ----------------
static const size_t OFF_KEYS = 0;          // ushort [64][512][512]  33,554,432
static const size_t OFF_WH   = 33554432;   // ushort [512][512]         524,288
static const size_t OFF_WHH0 = 34078720;   // ushort [1536][512]      1,572,864
static const size_t OFF_WIH1 = 35651584;   // ushort [1536][512]      1,572,864
static const size_t OFF_WHH1 = 37224448;   // ushort [1536][512]      1,572,864
static const size_t OFF_WIHC = 38797312;   // ushort [1536][256]        786,432
static const size_t OFF_GTOK = 39583744;   // float  [6][1536]           36,864
static const size_t OFF_H0   = 39620608;   // float  [64][512]          131,072
static const size_t OFF_H1   = 39751680;   // float  [64][512]          131,072
static const size_t OFF_QQ   = 39882752;   // float  [64][4][512]       524,288
static const size_t OFF_CTXP = 40407040;   // float  [64][4][256]       262,144
static const size_t OFF_SS   = 40669184;   // float  [64][4]              1,024
static const size_t OFF_H0Q  = 40670208;   // float  [64][4][128]       131,072
static const size_t OFF_H1Q  = 40801280;   // float  [64][4][128]       131,072
static const size_t OFF_FLG  = 40932352;   // uint   [256] x 64B lines   16,384
static const size_t OFF_LP   = 40948736;   // float  [512][64][16]    2,097,152
// end ~43 MB

// ---------------- dynamic LDS layout (bytes) ----------------
#define L_KEYS 0          // 131072 swizzled keys quarter [128][512] bf16
#define L_H0F  131072     // 2048  h0 full f32
#define L_H1F  133120     // 2048  h1 full f32
#define L_Q    135168     // 2176  q padded f32 [4][136]
#define L_VV   137344     // 2176  v padded f32
#define L_CTX  139520     // 1024  ctx f32 [256]
#define L_SCB  140544     // 512   scores [128]
#define L_ATB  141056     // 512   exp(scores) [128]
#define L_CT   141568     // 1024  ctmp f32 [256]
#define L_RED  142592     // 64    wave-reduce scratch
#define L_PRED 142656     // 12288 pRed f32 [4][6][128]
#define L_GH0  154944     // 1536  gh0own [3][128]
#define L_GH1  156480     // 1536  gh1own [3][128]
#define L_TOT  158016

// padded q index: quarter p starts at p*136 floats
__device__ __forceinline__ int qidx(int h) { return h + ((h >> 7) << 3); }

// ---------------- helpers ----------------
__device__ __forceinline__ float bfu(unsigned short u) {
  return __uint_as_float(((unsigned)u) << 16);
}
__device__ __forceinline__ float bflo(uint u) { return __uint_as_float(u << 16); }
__device__ __forceinline__ float bfhi(uint u) { return __uint_as_float(u & 0xffff0000u); }
__device__ __forceinline__ unsigned short f2bf(float f) {
  unsigned u = __float_as_uint(f);
  unsigned r = 0x7FFFu + ((u >> 16) & 1u);
  return (unsigned short)((u + r) >> 16);
}
__device__ __forceinline__ float tanh_fast(float x) {
  x = __builtin_amdgcn_fmed3f(x, -10.f, 10.f);
  float t = __builtin_amdgcn_exp2f(x * 2.8853900817779268f);
  return (t - 1.f) * __builtin_amdgcn_rcpf(t + 1.f);
}
__device__ __forceinline__ float sigmoid_fast(float x) {
  x = __builtin_amdgcn_fmed3f(x, -30.f, 30.f);
  float t = __builtin_amdgcn_exp2f(x * -1.4426950408889634f);
  return __builtin_amdgcn_rcpf(1.f + t);
}
__device__ __forceinline__ float exp_fast(float x) {
  return __builtin_amdgcn_exp2f(x * 1.4426950408889634f);
}
__device__ __forceinline__ float gloadf(const float* p) {
  return __hip_atomic_load(p, __ATOMIC_RELAXED, __HIP_MEMORY_SCOPE_AGENT);
}
__device__ __forceinline__ void gstoref(float* p, float v) {
  __hip_atomic_store(p, v, __ATOMIC_RELAXED, __HIP_MEMORY_SCOPE_AGENT);
}
__device__ __forceinline__ uint gloadu(const uint* p) {
  return __hip_atomic_load(p, __ATOMIC_RELAXED, __HIP_MEMORY_SCOPE_AGENT);
}
__device__ __forceinline__ void gstoreu(uint* p, uint v) {
  __hip_atomic_store(p, v, __ATOMIC_RELAXED, __HIP_MEMORY_SCOPE_AGENT);
}

// quad barrier: drain vmem, tid0 publishes flag=gen, spins (relaxed) on the
// 3 siblings' flags.
__device__ __forceinline__ void quad_sync(char* ws, int b, int j, uint gen) {
  asm volatile("s_waitcnt vmcnt(0)" ::: "memory");
  __syncthreads();
  if (threadIdx.x == 0) {
    uint* fl = (uint*)(ws + OFF_FLG);
    gstoreu(fl + (size_t)(b * 4 + j) * 16, gen);
    #pragma unroll
    for (int p = 0; p < 4; ++p) {
      if (p == j) continue;
      while (gloadu(fl + (size_t)(b * 4 + p) * 16) < gen)
        __builtin_amdgcn_s_sleep(4);
    }
  }
  __syncthreads();
}

// ---------------- precompute kernels ----------------

__global__ void k_prep(const float* Wh, const float* Whh0, const float* Wih0,
                       const float* Wih1, const float* Whh1, char* ws) {
  unsigned short* Whbf   = (unsigned short*)(ws + OFF_WH);
  unsigned short* Whh0bf = (unsigned short*)(ws + OFF_WHH0);
  unsigned short* Wih1bf = (unsigned short*)(ws + OFF_WIH1);
  unsigned short* Whh1bf = (unsigned short*)(ws + OFF_WHH1);
  unsigned short* WihCbf = (unsigned short*)(ws + OFF_WIHC);
  const int tot = 262144 + 786432 * 3 + 393216;
  for (int i = blockIdx.x * blockDim.x + threadIdx.x; i < tot; i += gridDim.x * blockDim.x) {
    if (i < 262144) { Whbf[i] = f2bf(Wh[i]); }
    else if (i < 262144 + 786432) { int jj = i - 262144; Whh0bf[jj] = f2bf(Whh0[jj]); }
    else if (i < 262144 + 2 * 786432) { int jj = i - 262144 - 786432; Wih1bf[jj] = f2bf(Wih1[jj]); }
    else if (i < 262144 + 3 * 786432) { int jj = i - 262144 - 2 * 786432; Whh1bf[jj] = f2bf(Whh1[jj]); }
    else {
      int jj = i - 262144 - 3 * 786432;
      int r = jj >> 8, e = jj & 255;
      WihCbf[jj] = f2bf(Wih0[(size_t)r * 384 + 128 + e]);
    }
  }
}

__global__ void k_gitok(const float* emb, const float* Wih0, const float* bih0, char* ws) {
  float* gt = (float*)(ws + OFF_GTOK);
  const int vt = blockIdx.x;
  const int tid = threadIdx.x;
  __shared__ float ev[EE];
  if (tid < EE) ev[tid] = emb[(size_t)vt * EE + tid];
  __syncthreads();
  for (int r = tid; r < 1536; r += 256) {
    float a = bih0[r];
    const float* wr = Wih0 + (size_t)r * 384;
    for (int e = 0; e < EE; ++e) a += wr[e] * ev[e];
    gt[(size_t)vt * 1536 + r] = a;
  }
}

__global__ void k_keys(const float* enc, const float* Ws, char* ws) {
  unsigned short* keys = (unsigned short*)(ws + OFF_KEYS);
  __shared__ float et[32][ED];
  const int tid = threadIdx.x;
  const int row0 = blockIdx.x * 32;
  for (int r = 0; r < 32; ++r) et[r][tid] = enc[(size_t)(row0 + r) * ED + tid];
  __syncthreads();
  for (int hhh = 0; hhh < 2; ++hhh) {
    const int h = hhh * 256 + tid;
    float acc[32];
    #pragma unroll
    for (int ll = 0; ll < 32; ++ll) acc[ll] = 0.f;
    const float4* wrow = (const float4*)(Ws + (size_t)h * ED);
    for (int e4 = 0; e4 < 64; ++e4) {
      float4 w = wrow[e4];
      #pragma unroll
      for (int ll = 0; ll < 32; ++ll) {
        acc[ll] += w.x * et[ll][e4 * 4] + w.y * et[ll][e4 * 4 + 1]
                 + w.z * et[ll][e4 * 4 + 2] + w.w * et[ll][e4 * 4 + 3];
      }
    }
    for (int ll = 0; ll < 32; ++ll)
      keys[(size_t)(row0 + ll) * HH + h] = f2bf(acc[ll]);
  }
}

__global__ void k_init(const float* enc, const float* Winit, const float* binit, char* ws) {
  const int b = blockIdx.x;
  const int tid = threadIdx.x; // 256
  __shared__ float pooled[ED];
  float acc = 0.f;
  for (int l = 0; l < LL; ++l) acc += enc[((size_t)b * LL + l) * ED + tid];
  pooled[tid] = acc * (1.0f / 512.0f);
  __syncthreads();
  float* h0 = (float*)(ws + OFF_H0);
  float* h1 = (float*)(ws + OFF_H1);
  for (int pass = 0; pass < 4; ++pass) {
    const int jj = pass * 256 + tid;
    float a = binit[jj];
    const float* wr = Winit + (size_t)jj * ED;
    for (int e = 0; e < ED; ++e) a += wr[e] * pooled[e];
    const float val = tanh_fast(a);
    const int nl = jj >> 9, h = jj & 511;
    if (nl == 0) h0[(size_t)b * HH + h] = val;
    else h1[(size_t)b * HH + h] = val;
  }
  if (b == 0) {
    uint* fl = (uint*)(ws + OFF_FLG);
    for (int i = tid; i < 4096; i += 256) fl[i] = 0u;
  }
}

// ---------------- main persistent decoder ----------------
__launch_bounds__(NTHR, 1)
__global__ void k_decode(char* ws, const float* enc, const int* targets,
                         const float* vvec, const float* bhh0, const float* bhh1,
                         const float* bih1, const float* Wout) {
  extern __shared__ char smem[];
  const int tid = threadIdx.x;
  const int blk = blockIdx.x;
  const int b = blk >> 2, j = blk & 3;

  const unsigned short* keysg  = (const unsigned short*)(ws + OFF_KEYS);
  const unsigned short* Whbf   = (const unsigned short*)(ws + OFF_WH);
  const unsigned short* Whh0bf = (const unsigned short*)(ws + OFF_WHH0);
  const unsigned short* Wih1bf = (const unsigned short*)(ws + OFF_WIH1);
  const unsigned short* Whh1bf = (const unsigned short*)(ws + OFF_WHH1);
  const unsigned short* WihCbf = (const unsigned short*)(ws + OFF_WIHC);
  const float* gi_tok = (const float*)(ws + OFF_GTOK);

  float* QQgf   = (float*)(ws + OFF_QQ)   + (size_t)b * 2048;  // [4][512]
  float* CTXPgf = (float*)(ws + OFF_CTXP) + (size_t)b * 1024;  // [4][256]
  float* SSg    = (float*)(ws + OFF_SS)   + (size_t)b * 4;     // [4]
  float* H0Qgf  = (float*)(ws + OFF_H0Q)  + (size_t)b * 512;   // [4][128]
  float* H1Qgf  = (float*)(ws + OFF_H1Q)  + (size_t)b * 512;   // [4][128]
  float* lp     = (float*)(ws + OFF_LP);

  float* h0f  = (float*)(smem + L_H0F);
  float* h1f  = (float*)(smem + L_H1F);
  float* qb   = (float*)(smem + L_Q);
  float* vvl  = (float*)(smem + L_VV);
  float* ctx  = (float*)(smem + L_CTX);
  float* scb  = (float*)(smem + L_SCB);
  float* atb  = (float*)(smem + L_ATB);
  float* ctmp = (float*)(smem + L_CT);
  float* wred = (float*)(smem + L_RED);
  float* pRed = (float*)(smem + L_PRED);
  float* gh0own = (float*)(smem + L_GH0);
  float* gh1own = (float*)(smem + L_GH1);

  const int r7 = tid & 127, seg = tid >> 7;

  // ---------- preloads (once) ----------
  // keys quarter -> LDS, swizzled: byte = l*1024 + ((h*2) ^ ((l&7)<<4))
  for (int idx = tid; idx < 8192; idx += NTHR) {
    const int l = idx >> 6, hs = idx & 63;
    ushort8 kv = *(const ushort8*)(keysg + ((size_t)(b * LL + j * 128 + l) * HH + hs * 8));
    *(ushort8*)(smem + L_KEYS + l * 1024 + ((hs * 16) ^ ((l & 7) << 4))) = kv;
  }
  vvl[qidx(tid)] = vvec[tid];
  h0f[tid] = ((const float*)(ws + OFF_H0))[(size_t)b * HH + tid];
  h1f[tid] = ((const float*)(ws + OFF_H1))[(size_t)b * HH + tid];

  // enc quarter slice -> 32 packed regs: thread (e=tid>>1, lh=tid&1), 64 l's
  uint encp[32];
  {
    const int e = tid >> 1, lh = tid & 1;
    const float* ebase = enc + ((size_t)(b * LL + j * 128 + lh * 64)) * ED + e;
    #pragma unroll
    for (int jj = 0; jj < 32; ++jj) {
      float a0 = ebase[(size_t)(2 * jj) * ED];
      float a1 = ebase[(size_t)(2 * jj + 1) * ED];
      encp[jj] = (uint)f2bf(a0) | ((uint)f2bf(a1) << 16);
    }
  }
  // Wh columns for own h1-slice: row tid, cols [j*128, +128) -> 64 uints
  uint whq[64];
  #pragma unroll
  for (int i = 0; i < 64; ++i)
    whq[i] = *(const uint*)(Whbf + (size_t)tid * HH + j * 128 + i * 2);

  __syncthreads();

  // pre-loop: publish q-partials AND initial own h1 slice (phase C of step -1)
  {
    float qr = 0.f;
    #pragma unroll 16
    for (int i = 0; i < 64; ++i)
      qr += bflo(whq[i]) * h1f[j * 128 + 2 * i] + bfhi(whq[i]) * h1f[j * 128 + 2 * i + 1];
    gstoref(QQgf + (size_t)j * 512 + tid, qr);
    if (tid < 128) gstoref(H1Qgf + (size_t)j * 128 + tid, h1f[j * 128 + tid]);
    quad_sync(ws, b, j, 1u);
  }

  for (int t = 0; t < LL; ++t) {
    // ================= PHASE A =================
    {
      // A1: update sibling h1 slices + assemble q from quad partials
      if (tid < 384) {
        const int ps = tid >> 7, i = tid & 127;
        const int p = ps + (ps >= j);
        h1f[p * 128 + i] = gloadf(H1Qgf + (size_t)p * 128 + i);
      }
      {
        float qv = gloadf(QQgf + 0 * 512 + tid) + gloadf(QQgf + 1 * 512 + tid)
                 + gloadf(QQgf + 2 * 512 + tid) + gloadf(QQgf + 3 * 512 + tid);
        qb[qidx(tid)] = qv;
      }
      __syncthreads();

      // A2: gh0/gh1 partials (weights streamed from L2, h from LDS broadcast)
      {
        float acc[6] = {0.f, 0.f, 0.f, 0.f, 0.f, 0.f};
        const int ks = seg * 128;
        #pragma unroll
        for (int g = 0; g < 3; ++g) {
          const ushort8* w0 = (const ushort8*)(Whh0bf + (size_t)(g * 512 + j * 128 + r7) * 512 + ks);
          const ushort8* w1 = (const ushort8*)(Whh1bf + (size_t)(g * 512 + j * 128 + r7) * 512 + ks);
          for (int k8 = 0; k8 < 16; ++k8) {
            ushort8 a8 = w0[k8];
            ushort8 b8 = w1[k8];
            #pragma unroll
            for (int u = 0; u < 8; ++u) {
              const float h0v = h0f[ks + k8 * 8 + u];
              const float h1v = h1f[ks + k8 * 8 + u];
              acc[g]     += bfu(a8[u]) * h0v;
              acc[3 + g] += bfu(b8[u]) * h1v;
            }
          }
        }
        #pragma unroll
        for (int u = 0; u < 6; ++u) pRed[(seg * 6 + u) * 128 + r7] = acc[u];
      }

      // A3: scores for own l-quarter (keys swizzled LDS, q padded LDS)
      {
        const int lloc = tid >> 2, hq = tid & 3;
        const char* kbase = smem + L_KEYS + lloc * 1024;
        const int xo = (lloc & 7) << 4;
        const float* qh = qb + hq * 136;
        const float* vh = vvl + hq * 136;
        float s = 0.f;
        #pragma unroll 4
        for (int i8 = 0; i8 < 16; ++i8) {
          ushort8 kk = *(const ushort8*)(kbase + ((hq * 256 + i8 * 16) ^ xo));
          #pragma unroll
          for (int u = 0; u < 8; ++u)
            s += vh[i8 * 8 + u] * tanh_fast(qh[i8 * 8 + u] + bfu(kk[u]));
        }
        s += __shfl_xor(s, 1);
        s += __shfl_xor(s, 2);
        if (hq == 0) scb[lloc] = s;
      }
      __syncthreads();

      // A4: exp (no max pass: |s| <= sum|v| ~ 20, safe in f32) + local sum
      {
        float e = 0.f;
        if (tid < 128) { e = exp_fast(scb[tid]); atb[tid] = e; }
        float s2 = e;
        #pragma unroll
        for (int off = 32; off >= 1; off >>= 1) s2 += __shfl_xor(s2, off);
        if ((tid & 63) == 0 && tid < 128) wred[tid >> 6] = s2;
      }
      __syncthreads();

      // A5: ctx partial (unnormalized) from enc regs; gh reduce
      {
        const int e = tid >> 1, lh = tid & 1;
        const float* atp = atb + lh * 64;
        float a = 0.f;
        #pragma unroll
        for (int jj = 0; jj < 32; ++jj) {
          uint u = encp[jj];
          a += atp[2 * jj] * bflo(u) + atp[2 * jj + 1] * bfhi(u);
        }
        a += __shfl_xor(a, 1);
        if (lh == 0) ctmp[e] = a;
      }
      if (tid < 384) {
        const int g = tid >> 7, r = tid & 127;
        gh0own[g * 128 + r] = pRed[(0 * 6 + g) * 128 + r] + pRed[(1 * 6 + g) * 128 + r]
                            + pRed[(2 * 6 + g) * 128 + r] + pRed[(3 * 6 + g) * 128 + r]
                            + bhh0[g * 512 + j * 128 + r];
        gh1own[g * 128 + r] = pRed[(0 * 6 + 3 + g) * 128 + r] + pRed[(1 * 6 + 3 + g) * 128 + r]
                            + pRed[(2 * 6 + 3 + g) * 128 + r] + pRed[(3 * 6 + 3 + g) * 128 + r]
                            + bhh1[g * 512 + j * 128 + r];
      }
      __syncthreads();

      // A6: publish ctx partial (f32) + S
      if (tid < 256) gstoref(CTXPgf + (size_t)j * 256 + tid, ctmp[tid]);
      if (tid == 0) gstoref(SSg + j, wred[0] + wred[1]);
    }
    quad_sync(ws, b, j, (uint)(3 * t + 2));

    // ================= PHASE B: ctx merge + gi0 + layer-0 gates ==============
    {
      if (tid < 256) {
        float S4 = gloadf(SSg + 0) + gloadf(SSg + 1) + gloadf(SSg + 2) + gloadf(SSg + 3);
        const float rS = __builtin_amdgcn_rcpf(S4);
        ctx[tid] = (gloadf(CTXPgf + 0 * 256 + tid) + gloadf(CTXPgf + 1 * 256 + tid)
                  + gloadf(CTXPgf + 2 * 256 + tid) + gloadf(CTXPgf + 3 * 256 + tid)) * rS;
      }
      __syncthreads();
      // gi0 partials: rows g*512 + j*128 + r7, K-span [seg*64,+64) of ctx
      {
        float acc[3] = {0.f, 0.f, 0.f};
        const int ks = seg * 64;
        #pragma unroll
        for (int g = 0; g < 3; ++g) {
          const ushort8* w = (const ushort8*)(WihCbf + (size_t)(g * 512 + j * 128 + r7) * 256 + ks);
          for (int k8 = 0; k8 < 8; ++k8) {
            ushort8 a8 = w[k8];
            #pragma unroll
            for (int u = 0; u < 8; ++u)
              acc[g] += bfu(a8[u]) * ctx[ks + k8 * 8 + u];
          }
        }
        #pragma unroll
        for (int g = 0; g < 3; ++g) pRed[(seg * 6 + g) * 128 + r7] = acc[g];
      }
      __syncthreads();
      if (tid < 128) {
        const int r = tid;
        const int tok = (t == 0) ? SOS : targets[(size_t)b * LL + t - 1];
        const float* gt = gi_tok + (size_t)tok * 1536 + j * 128 + r;
        float gi[3];
        #pragma unroll
        for (int g = 0; g < 3; ++g)
          gi[g] = pRed[(0 * 6 + g) * 128 + r] + pRed[(1 * 6 + g) * 128 + r]
                + pRed[(2 * 6 + g) * 128 + r] + pRed[(3 * 6 + g) * 128 + r]
                + gt[g * 512];
        const float rg = sigmoid_fast(gi[0] + gh0own[0 * 128 + r]);
        const float zg = sigmoid_fast(gi[1] + gh0own[1 * 128 + r]);
        const float ng = tanh_fast(gi[2] + rg * gh0own[2 * 128 + r]);
        h0f[j * 128 + r] = (1.f - zg) * ng + zg * h0f[j * 128 + r];
      }
      __syncthreads();
      if (tid < 128) gstoref(H0Qgf + (size_t)j * 128 + tid, h0f[j * 128 + tid]);
    }
    quad_sync(ws, b, j, (uint)(3 * t + 3));

    // update sibling h0 slices
    if (tid < 384) {
      const int ps = tid >> 7, i = tid & 127;
      const int p = ps + (ps >= j);
      h0f[p * 128 + i] = gloadf(H0Qgf + (size_t)p * 128 + i);
    }
    __syncthreads();

    // ================= PHASE C: gi1 + layer-1 gates + qpart + logits =========
    {
      // gi1 partials: rows g*512 + j*128 + r7, K-span [seg*128,+128) of h0f
      {
        float acc[3] = {0.f, 0.f, 0.f};
        const int ks = seg * 128;
        #pragma unroll
        for (int g = 0; g < 3; ++g) {
          const ushort8* w = (const ushort8*)(Wih1bf + (size_t)(g * 512 + j * 128 + r7) * 512 + ks);
          for (int k8 = 0; k8 < 16; ++k8) {
            ushort8 a8 = w[k8];
            #pragma unroll
            for (int u = 0; u < 8; ++u)
              acc[g] += bfu(a8[u]) * h0f[ks + k8 * 8 + u];
          }
        }
        #pragma unroll
        for (int g = 0; g < 3; ++g) pRed[(seg * 6 + g) * 128 + r7] = acc[g];
      }
      __syncthreads();
      if (tid < 128) {
        const int r = tid;
        float gi[3];
        #pragma unroll
        for (int g = 0; g < 3; ++g)
          gi[g] = pRed[(0 * 6 + g) * 128 + r] + pRed[(1 * 6 + g) * 128 + r]
                + pRed[(2 * 6 + g) * 128 + r] + pRed[(3 * 6 + g) * 128 + r]
                + bih1[g * 512 + j * 128 + r];
        const float rg = sigmoid_fast(gi[0] + gh1own[0 * 128 + r]);
        const float zg = sigmoid_fast(gi[1] + gh1own[1 * 128 + r]);
        const float ng = tanh_fast(gi[2] + rg * gh1own[2 * 128 + r]);
        h1f[j * 128 + r] = (1.f - zg) * ng + zg * h1f[j * 128 + r];
      }
      __syncthreads();
      // qpart (Wh columns in regs . new own h1 slice) — published straight
      {
        float qr = 0.f;
        #pragma unroll 16
        for (int i = 0; i < 64; ++i)
          qr += bflo(whq[i]) * h1f[j * 128 + 2 * i] + bfhi(whq[i]) * h1f[j * 128 + 2 * i + 1];
        gstoref(QQgf + (size_t)j * 512 + tid, qr);
      }
      if (tid < 128) gstoref(H1Qgf + (size_t)j * 128 + tid, h1f[j * 128 + tid]);
      // logit partials: threads 128..255 -> (v = g>>5, lanes g&31 over 4 elems)
      if (tid >= 128 && tid < 256) {
        const int g = tid - 128;
        const int v = g >> 5, i = g & 31;
        float a = 0.f;
        #pragma unroll
        for (int k = 0; k < 4; ++k)
          a += Wout[(size_t)v * HH + j * 128 + i * 4 + k] * h1f[j * 128 + i * 4 + k];
        a += __shfl_xor(a, 16); a += __shfl_xor(a, 8);
        a += __shfl_xor(a, 4);  a += __shfl_xor(a, 2); a += __shfl_xor(a, 1);
        if (i == 0) lp[((size_t)t * BB + b) * 16 + j * 4 + v] = a;
      }
    }
    quad_sync(ws, b, j, (uint)(3 * t + 4));
  }
}

// sum logit partials -> out
__global__ void k_lsum(const char* ws, const float* bout, float* out) {
  const float* lp = (const float*)(ws + OFF_LP);
  const int i = blockIdx.x * 256 + threadIdx.x;
  if (i >= BB * LL * VV) return;
  const int v = i & 3, t = (i >> 2) & 511, b = i >> 11;
  float a = bout[v];
  #pragma unroll
  for (int jj = 0; jj < 4; ++jj)
    a += lp[((size_t)t * BB + b) * 16 + jj * 4 + v];
  out[i] = a;
}

// ---------------- launch ----------------
extern "C" void kernel_launch(void* const* d_in, const int* in_sizes, int n_in,
                              void* d_out, int out_size, void* d_ws, size_t ws_size,
                              hipStream_t stream) {
  char* ws = (char*)d_ws;
  const float* enc     = (const float*)d_in[0];
  const int*   targets = (const int*)d_in[1];
  const float* emb   = (const float*)d_in[4];
  const float* Wh    = (const float*)d_in[5];
  const float* Ws    = (const float*)d_in[6];
  const float* vvec  = (const float*)d_in[7];
  const float* Wih0  = (const float*)d_in[8];
  const float* Whh0  = (const float*)d_in[9];
  const float* bih0  = (const float*)d_in[10];
  const float* bhh0  = (const float*)d_in[11];
  const float* Wih1  = (const float*)d_in[12];
  const float* Whh1  = (const float*)d_in[13];
  const float* bih1  = (const float*)d_in[14];
  const float* bhh1  = (const float*)d_in[15];
  const float* Wout  = (const float*)d_in[16];
  const float* bout  = (const float*)d_in[17];
  const float* Winit = (const float*)d_in[18];
  const float* binit = (const float*)d_in[19];

  k_prep <<<1024, 256, 0, stream>>>(Wh, Whh0, Wih0, Wih1, Whh1, ws);
  k_gitok<<<6,    256, 0, stream>>>(emb, Wih0, bih0, ws);
  k_keys <<<1024, 256, 0, stream>>>(enc, Ws, ws);
  k_init <<<64,   256, 0, stream>>>(enc, Winit, binit, ws);

  (void)hipFuncSetAttribute((const void*)k_decode,
                            hipFuncAttributeMaxDynamicSharedMemorySize, L_TOT);

  {
    void* kws = (void*)ws;
    void* ken = (void*)enc;
    void* ktg = (void*)targets;
    void* kvv = (void*)vvec;
    void* kb0 = (void*)bhh0;
    void* kb1 = (void*)bhh1;
    void* kbi = (void*)bih1;
    void* kwo = (void*)Wout;
    void* args[] = { &kws, &ken, &ktg, &kvv, &kb0, &kb1, &kbi, &kwo };
    hipError_t ce = hipLaunchCooperativeKernel((const void*)k_decode, dim3(NBLK), dim3(NTHR),
                                               args, L_TOT, stream);
    if (ce != hipSuccess) {
      // 256 blocks x (512 thr, 158KB LDS) = 1 block/CU on 256 CUs: co-resident
      k_decode<<<dim3(NBLK), dim3(NTHR), L_TOT, stream>>>(ws, enc, targets, vvec,
                                                          bhh0, bhh1, bih1, Wout);
    }
  }

  k_lsum<<<512, 256, 0, stream>>>(ws, bout, (float*)d_out);
}